// Round 5
// baseline (1545.033 us; speedup 1.0000x reference)
//
#include <hip/hip_runtime.h>
#include <hip/hip_bf16.h>

#define BN 32
#define CC 128
#define NN 2025
#define KK 9
#define NGROUP 4
#define CPG 32
#define GN_EPS 1e-5f
#define ROWS_TOTAL (BN * NN)   // 64800
#define BADCAP 4096

typedef _Float16 f16;
typedef __attribute__((ext_vector_type(2))) _Float16 f16x2;
typedef __attribute__((ext_vector_type(8))) _Float16 f16x8;
typedef __attribute__((ext_vector_type(4))) float f32x4;

#define S28 3.725290298461914e-09f   // 2^-28
#define S40 9.094947017729282e-13f   // 2^-40
#define RH  6.103515625e-05f         // 2^-14
#define RL  1.4901161193847656e-08f  // 2^-26
#define NEG_INF -3.0e38f

// ---------------- Kernel 1: L2 normalize -> scaled f16 split, coalesced ----------------
__global__ __launch_bounds__(256) void k_normalize(const float* __restrict__ x,
                                                   f16* __restrict__ xh, f16* __restrict__ xl) {
    __shared__ float tile[64 * 129];
    __shared__ float ssp[4][64];
    __shared__ float invl[64];
    int b = blockIdx.y, n0 = blockIdx.x * 64;
    int t = threadIdx.x, w = t >> 6, l = t & 63;
    const float* xb = x + (size_t)b * CC * NN;
    int n = min(n0 + l, NN - 1);
    float ss = 0.f;
#pragma unroll 8
    for (int cc = 0; cc < 32; ++cc) {
        int c = w * 32 + cc;
        float v = xb[(size_t)c * NN + n];
        tile[l * 129 + c] = v;
        ss += v * v;
    }
    ssp[w][l] = ss;
    __syncthreads();
    if (t < 64) {
        float tot = ssp[0][t] + ssp[1][t] + ssp[2][t] + ssp[3][t];
        invl[t] = 16384.0f / fmaxf(sqrtf(tot), 1e-12f);
    }
    __syncthreads();
    size_t base = ((size_t)b * NN + n0) * CC;
#pragma unroll 4
    for (int j = 0; j < 16; ++j) {
        int e2 = (j * 256 + t) * 2;
        int nl2 = e2 >> 7, c2 = e2 & 127;
        if (n0 + nl2 < NN) {
            float inv = invl[nl2];
            float a0 = tile[nl2 * 129 + c2] * inv;
            float a1 = tile[nl2 * 129 + c2 + 1] * inv;
            f16 h0 = (f16)a0, h1 = (f16)a1;
            f16 lo0 = (f16)((a0 - (float)h0) * 4096.0f);
            f16 lo1 = (f16)((a1 - (float)h1) * 4096.0f);
            *(f16x2*)(xh + base + e2) = (f16x2){h0, h1};
            *(f16x2*)(xl + base + e2) = (f16x2){lo0, lo1};
        }
    }
}

// top-9 insert: (value desc, index asc) ordering; order-independent tie rules
__device__ __forceinline__ void ins9(float cand, int m, float* v, int* ix,
                                     float& mv, int& mi, int& mp) {
    bool take = (cand > mv) || ((cand == mv) && (m < mi));
    if (take) {
#pragma unroll
        for (int k = 0; k < 9; ++k) if (k == mp) { v[k] = cand; ix[k] = m; }
        float nv = v[0]; int ni = ix[0]; int np = 0;
#pragma unroll
        for (int k = 1; k < 9; ++k) {
            if (v[k] < nv || (v[k] == nv && ix[k] > ni)) { nv = v[k]; ni = ix[k]; np = k; }
        }
        mv = nv; mi = ni; mp = np;
    }
}

// branch-free sorted (desc) top-4 insert; within-lane m ascends so ties auto-resolve
#define INS4(c, m, V, I)                                            \
    {                                                               \
        bool b0 = (c) > V[0], b1 = (c) > V[1], b2 = (c) > V[2], b3 = (c) > V[3]; \
        V[3] = b3 ? (b2 ? V[2] : (c)) : V[3];  I[3] = b3 ? (b2 ? I[2] : (m)) : I[3]; \
        V[2] = b2 ? (b1 ? V[1] : (c)) : V[2];  I[2] = b2 ? (b1 ? I[1] : (m)) : I[2]; \
        V[1] = b1 ? (b0 ? V[0] : (c)) : V[1];  I[1] = b1 ? (b0 ? I[0] : (m)) : I[1]; \
        V[0] = b0 ? (c) : V[0];                I[0] = b0 ? (m) : I[0]; \
    }

// ---------------- Kernel 2: fused sim + top-k: MFMA + per-lane register top-4 segments ----------------
__global__ __launch_bounds__(256) void k_sim_topk(const f16* __restrict__ xh, const f16* __restrict__ xl,
                                                  float* __restrict__ vout, int* __restrict__ iout,
                                                  int* __restrict__ badcnt, int* __restrict__ badlist) {
    __shared__ float svf[32 * 16 * 4];
    __shared__ int   sii[32 * 16 * 4];

    const int b    = blockIdx.y;
    const int r0   = blockIdx.x * 32;
    const int t    = threadIdx.x;
    const int w    = t >> 6;
    const int lane = t & 63;
    const int jr   = lane & 15;
    const int q    = lane >> 4;

    // B fragments: rows r0+tile*16+jr, 4 K-steps of 32, lane's k-window = s*32 + q*8
    f16x8 bh[2][4], bl[2][4];
#pragma unroll
    for (int tile = 0; tile < 2; ++tile) {
        int rr = b * NN + min(r0 + tile * 16 + jr, NN - 1);
        const f16* pH = xh + (size_t)rr * CC;
        const f16* pL = xl + (size_t)rr * CC;
#pragma unroll
        for (int s = 0; s < 4; ++s) {
            bh[tile][s] = *(const f16x8*)(pH + s * 32 + q * 8);
            bl[tile][s] = *(const f16x8*)(pL + s * 32 + q * 8);
        }
    }

    // per-lane sorted top-4 segment lists, one per row-tile
    float sgv[2][4]; int sgi[2][4];
#pragma unroll
    for (int tile = 0; tile < 2; ++tile)
#pragma unroll
        for (int k = 0; k < 4; ++k) { sgv[tile][k] = NEG_INF; sgi[tile][k] = 0x7fffffff; }

    for (int chunk = 0; chunk < 32; ++chunk) {
        const int mb = chunk * 64 + w * 16;
        const int marow = b * NN + min(mb + jr, NN - 1);
        const f16* aHp = xh + (size_t)marow * CC;
        const f16* aLp = xl + (size_t)marow * CC;
        f32x4 h0 = {0.f, 0.f, 0.f, 0.f}, l0 = {0.f, 0.f, 0.f, 0.f};
        f32x4 h1 = {0.f, 0.f, 0.f, 0.f}, l1 = {0.f, 0.f, 0.f, 0.f};
#pragma unroll
        for (int s = 0; s < 4; ++s) {
            f16x8 ah = *(const f16x8*)(aHp + s * 32 + q * 8);
            f16x8 al = *(const f16x8*)(aLp + s * 32 + q * 8);
            h0 = __builtin_amdgcn_mfma_f32_16x16x32_f16(ah, bh[0][s], h0, 0, 0, 0);
            l0 = __builtin_amdgcn_mfma_f32_16x16x32_f16(ah, bl[0][s], l0, 0, 0, 0);
            l0 = __builtin_amdgcn_mfma_f32_16x16x32_f16(al, bh[0][s], l0, 0, 0, 0);
            h1 = __builtin_amdgcn_mfma_f32_16x16x32_f16(ah, bh[1][s], h1, 0, 0, 0);
            l1 = __builtin_amdgcn_mfma_f32_16x16x32_f16(ah, bl[1][s], l1, 0, 0, 0);
            l1 = __builtin_amdgcn_mfma_f32_16x16x32_f16(al, bh[1][s], l1, 0, 0, 0);
        }
#pragma unroll
        for (int reg = 0; reg < 4; ++reg) {
            int m = mb + q * 4 + reg;
            bool ok = (m < NN);
            float c0 = h0[reg] * S28 + l0[reg] * S40;
            c0 = ok ? c0 : NEG_INF;
            INS4(c0, m, sgv[0], sgi[0]);
            float c1 = h1[reg] * S28 + l1[reg] * S40;
            c1 = ok ? c1 : NEG_INF;
            INS4(c1, m, sgv[1], sgi[1]);
        }
    }

    // write segments to LDS: row = tile*16+jr, seg = w*4+q
    int seg = w * 4 + q;
#pragma unroll
    for (int tile = 0; tile < 2; ++tile) {
        int row = tile * 16 + jr;
        int base = (row * 16 + seg) * 4;
#pragma unroll
        for (int k = 0; k < 4; ++k) { svf[base + k] = sgv[tile][k]; sii[base + k] = sgi[tile][k]; }
    }
    __syncthreads();

    // merge: wave 0, two lanes per row (t and t+32), 8 segments each
    if (t < 64) {
        int row = t & 31, half = t >> 5;
        float fv[9]; int fi[9];
#pragma unroll
        for (int k = 0; k < 9; ++k) { fv[k] = NEG_INF; fi[k] = 0x7fffffff; }
        float mv = NEG_INF; int mi = 0x7fffffff; int mp = 0;
        for (int s = half * 8; s < half * 8 + 8; ++s) {
            int base = (row * 16 + s) * 4;
#pragma unroll
            for (int k = 0; k < 4; ++k) ins9(svf[base + k], sii[base + k], fv, fi, mv, mi, mp);
        }
        // combine halves via shfl (both lanes active)
        float pv[9]; int pi[9];
#pragma unroll
        for (int k = 0; k < 9; ++k) { pv[k] = __shfl_xor(fv[k], 32); pi[k] = __shfl_xor(fi[k], 32); }
#pragma unroll
        for (int k = 0; k < 9; ++k) ins9(pv[k], pi[k], fv, fi, mv, mi, mp);

        if (t < 32) {
            int r = r0 + row;
            if (r < NN) {
                // detection: any segment's kept-4th strictly beats the merged 9th
                bool bad = false;
#pragma unroll 4
                for (int s = 0; s < 16; ++s) {
                    float v3 = svf[(row * 16 + s) * 4 + 3];
                    int   i3 = sii[(row * 16 + s) * 4 + 3];
                    bad = bad || (v3 > mv) || (v3 == mv && i3 < mi);
                }
                if (bad) {
                    int pos = atomicAdd(badcnt, 1);
                    if (pos < BADCAP) badlist[pos] = (b << 12) | r;
                }
                float s = 1e-6f;
#pragma unroll
                for (int k = 0; k < 9; ++k) s += fv[k];
                float inv = 1.0f / s;
                int base = (b * NN + r) * KK;
#pragma unroll
                for (int k = 0; k < 9; ++k) { vout[base + k] = fv[k] * inv; iout[base + k] = fi[k]; }
            }
        }
    }
}

// ---------------- Kernel 2b: exact re-solve of flagged rows ----------------
__global__ __launch_bounds__(256) void k_topk_fix(const f16* __restrict__ xh, const f16* __restrict__ xl,
                                                  const int* __restrict__ badcnt, const int* __restrict__ badlist,
                                                  float* __restrict__ vout, int* __restrict__ iout) {
    __shared__ float wvs[4][9];
    __shared__ int   wis[4][9];
    int nb = min(badcnt[0], BADCAP);
    int t = threadIdx.x, w = t >> 6, lane = t & 63;
    for (int i = blockIdx.x; i < nb; i += gridDim.x) {
        __syncthreads();
        int id = badlist[i];
        int b = id >> 12, r = id & 4095;
        const f16* rH = xh + ((size_t)b * NN + r) * CC;
        const f16* rL = xl + ((size_t)b * NN + r) * CC;
        float fv[9]; int fi[9];
#pragma unroll
        for (int k = 0; k < 9; ++k) { fv[k] = NEG_INF; fi[k] = 0x7fffffff; }
        float mv = NEG_INF; int mi = 0x7fffffff; int mp = 0;
        for (int m = t; m < NN; m += 256) {
            const f16* mH = xh + ((size_t)b * NN + m) * CC;
            const f16* mL = xl + ((size_t)b * NN + m) * CC;
            float a1 = 0.f, a2 = 0.f;
            for (int c = 0; c < CC; ++c) {
                float hr = (float)rH[c], hm = (float)mH[c];
                float lr = (float)rL[c], lm = (float)mL[c];
                a1 += hr * hm;
                a2 += hr * lm + lr * hm;
            }
            ins9(a1 * S28 + a2 * S40, m, fv, fi, mv, mi, mp);
        }
#pragma unroll
        for (int off = 1; off < 64; off <<= 1) {
            float pv[9]; int pi[9];
#pragma unroll
            for (int k = 0; k < 9; ++k) { pv[k] = __shfl_xor(fv[k], off); pi[k] = __shfl_xor(fi[k], off); }
#pragma unroll
            for (int k = 0; k < 9; ++k) ins9(pv[k], pi[k], fv, fi, mv, mi, mp);
        }
        if (lane == 0) {
#pragma unroll
            for (int k = 0; k < 9; ++k) { wvs[w][k] = fv[k]; wis[w][k] = fi[k]; }
        }
        __syncthreads();
        if (t == 0) {
            for (int ww = 1; ww < 4; ++ww)
#pragma unroll
                for (int k = 0; k < 9; ++k) ins9(wvs[ww][k], wis[ww][k], fv, fi, mv, mi, mp);
            float s = 1e-6f;
#pragma unroll
            for (int k = 0; k < 9; ++k) s += fv[k];
            float inv = 1.0f / s;
            int base = (b * NN + r) * KK;
#pragma unroll
            for (int k = 0; k < 9; ++k) { vout[base + k] = fv[k] * inv; iout[base + k] = fi[k]; }
        }
    }
}

// ---------------- Kernel 3a: GEMM out = reconstruct(xh,xl) @ w  (layer 1) ----------------
#define RST 36
__global__ __launch_bounds__(256) void k_gemm_hl(const f16* __restrict__ xh, const f16* __restrict__ xl,
                                                 const float* __restrict__ w, float* __restrict__ out) {
    __shared__ float rowsT[CC * RST];
    int t = threadIdx.x;
    int row0 = blockIdx.x * 32;
    for (int it = 0; it < 16; ++it) {
        int qq = t + it * 256;
        int c = qq & 127, r = qq >> 7;
        size_t idx = (size_t)(row0 + r) * CC + c;
        rowsT[c * RST + r] = (float)xh[idx] * RH + (float)xl[idx] * RL;
    }
    __syncthreads();
    int j = t & 127, half = t >> 7;
    float acc[16];
#pragma unroll
    for (int r = 0; r < 16; ++r) acc[r] = 0.0f;
    for (int c = 0; c < CC; ++c) {
        float wv = w[c * CC + j];
        const float4* ap = (const float4*)&rowsT[c * RST + half * 16];
        float4 a0 = ap[0], a1 = ap[1], a2 = ap[2], a3 = ap[3];
        acc[0]  += a0.x * wv; acc[1]  += a0.y * wv; acc[2]  += a0.z * wv; acc[3]  += a0.w * wv;
        acc[4]  += a1.x * wv; acc[5]  += a1.y * wv; acc[6]  += a1.z * wv; acc[7]  += a1.w * wv;
        acc[8]  += a2.x * wv; acc[9]  += a2.y * wv; acc[10] += a2.z * wv; acc[11] += a2.w * wv;
        acc[12] += a3.x * wv; acc[13] += a3.y * wv; acc[14] += a3.z * wv; acc[15] += a3.w * wv;
    }
#pragma unroll
    for (int r = 0; r < 16; ++r) out[(size_t)(row0 + half * 16 + r) * CC + j] = acc[r];
}

// ---------------- Kernel 3b: GEMM fp32 in (layer 2) ----------------
__global__ __launch_bounds__(256) void k_gemm(const float* __restrict__ in,
                                              const float* __restrict__ w,
                                              float* __restrict__ out) {
    __shared__ float rowsT[CC * RST];
    int t = threadIdx.x;
    int row0 = blockIdx.x * 32;
    for (int it = 0; it < 16; ++it) {
        int qq = t + it * 256;
        int c = qq & 127, r = qq >> 7;
        rowsT[c * RST + r] = in[(size_t)(row0 + r) * CC + c];
    }
    __syncthreads();
    int j = t & 127, half = t >> 7;
    float acc[16];
#pragma unroll
    for (int r = 0; r < 16; ++r) acc[r] = 0.0f;
    for (int c = 0; c < CC; ++c) {
        float wv = w[c * CC + j];
        const float4* ap = (const float4*)&rowsT[c * RST + half * 16];
        float4 a0 = ap[0], a1 = ap[1], a2 = ap[2], a3 = ap[3];
        acc[0]  += a0.x * wv; acc[1]  += a0.y * wv; acc[2]  += a0.z * wv; acc[3]  += a0.w * wv;
        acc[4]  += a1.x * wv; acc[5]  += a1.y * wv; acc[6]  += a1.z * wv; acc[7]  += a1.w * wv;
        acc[8]  += a2.x * wv; acc[9]  += a2.y * wv; acc[10] += a2.z * wv; acc[11] += a2.w * wv;
        acc[12] += a3.x * wv; acc[13] += a3.y * wv; acc[14] += a3.z * wv; acc[15] += a3.w * wv;
    }
#pragma unroll
    for (int r = 0; r < 16; ++r) out[(size_t)(row0 + half * 16 + r) * CC + j] = acc[r];
}

// ---------------- Kernel 4: gather + weighted sum + bias ----------------
__global__ __launch_bounds__(256) void k_gather(const float* __restrict__ xt,
                                                const float* __restrict__ v,
                                                const int* __restrict__ idx,
                                                const float* __restrict__ bias,
                                                float* __restrict__ out) {
    int t = threadIdx.x;
    int g = blockIdx.x * 2 + (t >> 7);
    int c = t & 127;
    if (g >= ROWS_TOTAL) return;
    int b = g / NN;
    int nb = b * NN;
    float acc = bias[c];
    int base = g * KK;
#pragma unroll
    for (int k = 0; k < KK; ++k) {
        int   ii = idx[base + k];
        float vv = v[base + k];
        acc += vv * xt[(size_t)(nb + ii) * CC + c];
    }
    out[(size_t)g * CC + c] = acc;
}

// ---------------- Kernel 5: GroupNorm stats per (b, group) ----------------
__global__ __launch_bounds__(256) void k_gnstats(const float* __restrict__ xin,
                                                 float* __restrict__ stats) {
    int bg = blockIdx.x; int b = bg >> 2; int gg = bg & 3;
    size_t base = (size_t)b * (NN * CC) + gg * CPG;
    float s1 = 0.f, s2 = 0.f;
    for (int i = threadIdx.x; i < NN * CPG; i += 256) {
        float x = xin[base + (size_t)(i >> 5) * CC + (i & 31)];
        s1 += x; s2 += x * x;
    }
#pragma unroll
    for (int off = 32; off > 0; off >>= 1) { s1 += __shfl_xor(s1, off); s2 += __shfl_xor(s2, off); }
    __shared__ float r1[4], r2[4];
    int w = threadIdx.x >> 6;
    if ((threadIdx.x & 63) == 0) { r1[w] = s1; r2[w] = s2; }
    __syncthreads();
    if (threadIdx.x == 0) {
        float a = r1[0] + r1[1] + r1[2] + r1[3];
        float qq = r2[0] + r2[1] + r2[2] + r2[3];
        const float inv = 1.0f / (float)(NN * CPG);
        float mean = a * inv;
        float var = qq * inv - mean * mean;
        stats[bg * 2]     = mean;
        stats[bg * 2 + 1] = rsqrtf(fmaxf(var, 0.f) + GN_EPS);
    }
}

// ---------------- Kernel 6: GN apply + SiLU (layout-preserving, fp32 out) ----------------
__global__ __launch_bounds__(256) void k_gnsilu(const float* __restrict__ xin,
                                                const float* __restrict__ stats,
                                                const float* __restrict__ gamma,
                                                const float* __restrict__ beta,
                                                float* __restrict__ out) {
    size_t e4 = ((size_t)blockIdx.x * 256 + threadIdx.x) * 4;
    int c0 = (int)(e4 & 127);
    int b  = (int)(e4 / (NN * CC));
    int gg = c0 >> 5;
    float mean = stats[(b * 4 + gg) * 2];
    float rstd = stats[(b * 4 + gg) * 2 + 1];
    float4 x = *(const float4*)&xin[e4];
    float g0 = gamma[c0], g1 = gamma[c0 + 1], g2 = gamma[c0 + 2], g3 = gamma[c0 + 3];
    float p0 = beta[c0],  p1 = beta[c0 + 1],  p2 = beta[c0 + 2],  p3 = beta[c0 + 3];
    float y0 = (x.x - mean) * rstd * g0 + p0;
    float y1 = (x.y - mean) * rstd * g1 + p1;
    float y2 = (x.z - mean) * rstd * g2 + p2;
    float y3 = (x.w - mean) * rstd * g3 + p3;
    float4 r;
    r.x = y0 / (1.0f + expf(-y0));
    r.y = y1 / (1.0f + expf(-y1));
    r.z = y2 / (1.0f + expf(-y2));
    r.w = y3 / (1.0f + expf(-y3));
    *(float4*)&out[e4] = r;
}

// ---------------- Kernel 7: GN apply + SiLU + transpose to [B][C][N], fp32 out ----------------
__global__ __launch_bounds__(256) void k_gnsilu_out(const float* __restrict__ xin,
                                                    const float* __restrict__ stats,
                                                    const float* __restrict__ gamma,
                                                    const float* __restrict__ beta,
                                                    float* __restrict__ out) {
    __shared__ float tile[32 * 65];
    int b = blockIdx.z, ct = blockIdx.y, nt = blockIdx.x;
    int c0 = ct * 32, n0 = nt * 64;
    int t = threadIdx.x;
    int cj = t & 31, ni0 = t >> 5;
    int gg = c0 >> 5;
    float mean = stats[(b * 4 + gg) * 2];
    float rstd = stats[(b * 4 + gg) * 2 + 1];
    float gm = gamma[c0 + cj];
    float bt = beta[c0 + cj];
#pragma unroll
    for (int i = 0; i < 8; ++i) {
        int n = n0 + ni0 + i * 8;
        if (n < NN) {
            float x = xin[((size_t)b * NN + n) * CC + c0 + cj];
            float y = (x - mean) * rstd * gm + bt;
            y = y / (1.0f + expf(-y));
            tile[cj * 65 + ni0 + i * 8] = y;
        }
    }
    __syncthreads();
    int nj = t & 63, ci0 = t >> 6;
#pragma unroll
    for (int i = 0; i < 8; ++i) {
        int c = ci0 + i * 4;
        int n = n0 + nj;
        if (n < NN) out[((size_t)b * CC + c0 + c) * NN + n] = tile[c * 65 + nj];
    }
}

extern "C" void kernel_launch(void* const* d_in, const int* in_sizes, int n_in,
                              void* d_out, int out_size, void* d_ws, size_t ws_size,
                              hipStream_t stream) {
    const float* x      = (const float*)d_in[0];
    const float* w1     = (const float*)d_in[1];
    const float* b1     = (const float*)d_in[2];
    const float* w2     = (const float*)d_in[3];
    const float* b2     = (const float*)d_in[4];
    const float* gamma1 = (const float*)d_in[5];
    const float* beta1  = (const float*)d_in[6];
    const float* gamma2 = (const float*)d_in[7];
    const float* beta2  = (const float*)d_in[8];
    float* out = (float*)d_out;

    const size_t BIG = (size_t)ROWS_TOTAL * CC;   // 8,294,400
    float* ws   = (float*)d_ws;
    float* bufB = ws;                              // gemm1out -> feat2 -> gath2
    f16*   xh   = (f16*)(ws + BIG);                // f16 split hi
    f16*   xl   = xh + BIG;                        // f16 split lo
    float* bufA = ws + BIG;                        // ALIASES xh/xl; first written by gather1
    float* vbuf = ws + 2 * BIG;                    // [64800*9]
    int*   ibuf = (int*)(ws + 2 * BIG + (size_t)ROWS_TOTAL * KK);
    float* stats = ws + 2 * BIG + 2 * (size_t)ROWS_TOTAL * KK;
    int*   badcnt  = (int*)(stats + 256);
    int*   badlist = badcnt + 1;

    hipMemsetAsync(badcnt, 0, sizeof(int), stream);

    k_normalize<<<dim3(32, BN), 256, 0, stream>>>(x, xh, xl);
    k_sim_topk<<<dim3(64, BN), 256, 0, stream>>>(xh, xl, vbuf, ibuf, badcnt, badlist);
    k_topk_fix<<<128, 256, 0, stream>>>(xh, xl, badcnt, badlist, vbuf, ibuf);

    // layer 1 (xh/xl last read by k_gemm_hl; bufA aliases them and is written after)
    k_gemm_hl<<<(ROWS_TOTAL + 31) / 32, 256, 0, stream>>>(xh, xl, w1, bufB);
    k_gather<<<ROWS_TOTAL / 2, 256, 0, stream>>>(bufB, vbuf, ibuf, b1, bufA);
    k_gnstats<<<BN * NGROUP, 256, 0, stream>>>(bufA, stats);
    k_gnsilu<<<(int)(BIG / 1024), 256, 0, stream>>>(bufA, stats, gamma1, beta1, bufB);

    // layer 2
    k_gemm<<<(ROWS_TOTAL + 31) / 32, 256, 0, stream>>>(bufB, w2, bufA);
    k_gather<<<ROWS_TOTAL / 2, 256, 0, stream>>>(bufA, vbuf, ibuf, b2, bufB);
    k_gnstats<<<BN * NGROUP, 256, 0, stream>>>(bufB, stats);
    k_gnsilu_out<<<dim3((NN + 63) / 64, NGROUP, BN), 256, 0, stream>>>(bufB, stats, gamma2, beta2, out);
}

// Round 8
// 792.401 us; speedup vs baseline: 1.9498x; 1.9498x over previous
//
#include <hip/hip_runtime.h>
#include <hip/hip_bf16.h>

#define BN 32
#define CC 128
#define NN 2025
#define KK 9
#define NGROUP 4
#define CPG 32
#define GN_EPS 1e-5f
#define ROWS_TOTAL (BN * NN)   // 64800
#define BADCAP 4096

typedef _Float16 f16;
typedef __attribute__((ext_vector_type(2))) _Float16 f16x2;
typedef __attribute__((ext_vector_type(8))) _Float16 f16x8;
typedef __attribute__((ext_vector_type(4))) float f32x4;

#define S28 3.725290298461914e-09f   // 2^-28
#define S40 9.094947017729282e-13f   // 2^-40
#define RH  6.103515625e-05f         // 2^-14
#define RL  1.4901161193847656e-08f  // 2^-26
#define NEG_INF -3.0e38f

// ---------------- Kernel 1: L2 normalize -> scaled f16 split, coalesced ----------------
__global__ __launch_bounds__(256) void k_normalize(const float* __restrict__ x,
                                                   f16* __restrict__ xh, f16* __restrict__ xl) {
    __shared__ float tile[64 * 129];
    __shared__ float ssp[4][64];
    __shared__ float invl[64];
    int b = blockIdx.y, n0 = blockIdx.x * 64;
    int t = threadIdx.x, w = t >> 6, l = t & 63;
    const float* xb = x + (size_t)b * CC * NN;
    int n = min(n0 + l, NN - 1);
    float ss = 0.f;
#pragma unroll 8
    for (int cc = 0; cc < 32; ++cc) {
        int c = w * 32 + cc;
        float v = xb[(size_t)c * NN + n];
        tile[l * 129 + c] = v;
        ss += v * v;
    }
    ssp[w][l] = ss;
    __syncthreads();
    if (t < 64) {
        float tot = ssp[0][t] + ssp[1][t] + ssp[2][t] + ssp[3][t];
        invl[t] = 16384.0f / fmaxf(sqrtf(tot), 1e-12f);
    }
    __syncthreads();
    size_t base = ((size_t)b * NN + n0) * CC;
#pragma unroll 4
    for (int j = 0; j < 16; ++j) {
        int e2 = (j * 256 + t) * 2;
        int nl2 = e2 >> 7, c2 = e2 & 127;
        if (n0 + nl2 < NN) {
            float inv = invl[nl2];
            float a0 = tile[nl2 * 129 + c2] * inv;
            float a1 = tile[nl2 * 129 + c2 + 1] * inv;
            f16 h0 = (f16)a0, h1 = (f16)a1;
            f16 lo0 = (f16)((a0 - (float)h0) * 4096.0f);
            f16 lo1 = (f16)((a1 - (float)h1) * 4096.0f);
            *(f16x2*)(xh + base + e2) = (f16x2){h0, h1};
            *(f16x2*)(xl + base + e2) = (f16x2){lo0, lo1};
        }
    }
}

// top-9 insert: (value desc, index asc) ordering; order-independent tie rules
__device__ __forceinline__ void ins9(float cand, int m, float* v, int* ix,
                                     float& mv, int& mi, int& mp) {
    bool take = (cand > mv) || ((cand == mv) && (m < mi));
    if (take) {
#pragma unroll
        for (int k = 0; k < 9; ++k) if (k == mp) { v[k] = cand; ix[k] = m; }
        float nv = v[0]; int ni = ix[0]; int np = 0;
#pragma unroll
        for (int k = 1; k < 9; ++k) {
            if (v[k] < nv || (v[k] == nv && ix[k] > ni)) { nv = v[k]; ni = ix[k]; np = k; }
        }
        mv = nv; mi = ni; mp = np;
    }
}

// branch-free sorted (desc) top-5 insert; within-lane m ascends so ties auto-resolve
#define INS5(c, m, V, I)                                            \
    {                                                               \
        bool b0 = (c) > V[0], b1 = (c) > V[1], b2 = (c) > V[2], b3 = (c) > V[3], b4 = (c) > V[4]; \
        V[4] = b4 ? (b3 ? V[3] : (c)) : V[4];  I[4] = b4 ? (b3 ? I[3] : (m)) : I[4]; \
        V[3] = b3 ? (b2 ? V[2] : (c)) : V[3];  I[3] = b3 ? (b2 ? I[2] : (m)) : I[3]; \
        V[2] = b2 ? (b1 ? V[1] : (c)) : V[2];  I[2] = b2 ? (b1 ? I[1] : (m)) : I[2]; \
        V[1] = b1 ? (b0 ? V[0] : (c)) : V[1];  I[1] = b1 ? (b0 ? I[0] : (m)) : I[1]; \
        V[0] = b0 ? (c) : V[0];                I[0] = b0 ? (m) : I[0]; \
    }

// ---------------- Kernel 2: fused sim + top-k: MFMA + per-lane register top-5 segments ----------------
__global__ __launch_bounds__(256) void k_sim_topk(const f16* __restrict__ xh, const f16* __restrict__ xl,
                                                  float* __restrict__ vout, int* __restrict__ iout,
                                                  int* __restrict__ badcnt, int* __restrict__ badlist) {
    __shared__ float svf[32 * 16 * 5];
    __shared__ int   sii[32 * 16 * 5];

    const int b    = blockIdx.y;
    const int r0   = blockIdx.x * 32;
    const int t    = threadIdx.x;
    const int w    = t >> 6;
    const int lane = t & 63;
    const int jr   = lane & 15;
    const int q    = lane >> 4;

    // B fragments: rows r0+tile*16+jr, 4 K-steps of 32, lane's k-window = s*32 + q*8
    f16x8 bh[2][4], bl[2][4];
#pragma unroll
    for (int tile = 0; tile < 2; ++tile) {
        int rr = b * NN + min(r0 + tile * 16 + jr, NN - 1);
        const f16* pH = xh + (size_t)rr * CC;
        const f16* pL = xl + (size_t)rr * CC;
#pragma unroll
        for (int s = 0; s < 4; ++s) {
            bh[tile][s] = *(const f16x8*)(pH + s * 32 + q * 8);
            bl[tile][s] = *(const f16x8*)(pL + s * 32 + q * 8);
        }
    }

    // per-lane sorted top-5 segment lists, one per row-tile
    float sgv[2][5]; int sgi[2][5];
#pragma unroll
    for (int tile = 0; tile < 2; ++tile)
#pragma unroll
        for (int k = 0; k < 5; ++k) { sgv[tile][k] = NEG_INF; sgi[tile][k] = 0x7fffffff; }

    for (int chunk = 0; chunk < 32; ++chunk) {
        const int mb = chunk * 64 + w * 16;
        const int marow = b * NN + min(mb + jr, NN - 1);
        const f16* aHp = xh + (size_t)marow * CC;
        const f16* aLp = xl + (size_t)marow * CC;
        f32x4 h0 = {0.f, 0.f, 0.f, 0.f}, l0 = {0.f, 0.f, 0.f, 0.f};
        f32x4 h1 = {0.f, 0.f, 0.f, 0.f}, l1 = {0.f, 0.f, 0.f, 0.f};
#pragma unroll
        for (int s = 0; s < 4; ++s) {
            f16x8 ah = *(const f16x8*)(aHp + s * 32 + q * 8);
            f16x8 al = *(const f16x8*)(aLp + s * 32 + q * 8);
            h0 = __builtin_amdgcn_mfma_f32_16x16x32_f16(ah, bh[0][s], h0, 0, 0, 0);
            l0 = __builtin_amdgcn_mfma_f32_16x16x32_f16(ah, bl[0][s], l0, 0, 0, 0);
            l0 = __builtin_amdgcn_mfma_f32_16x16x32_f16(al, bh[0][s], l0, 0, 0, 0);
            h1 = __builtin_amdgcn_mfma_f32_16x16x32_f16(ah, bh[1][s], h1, 0, 0, 0);
            l1 = __builtin_amdgcn_mfma_f32_16x16x32_f16(ah, bl[1][s], l1, 0, 0, 0);
            l1 = __builtin_amdgcn_mfma_f32_16x16x32_f16(al, bh[1][s], l1, 0, 0, 0);
        }
#pragma unroll
        for (int reg = 0; reg < 4; ++reg) {
            int m = mb + q * 4 + reg;
            bool ok = (m < NN);
            float c0 = h0[reg] * S28 + l0[reg] * S40;
            c0 = ok ? c0 : NEG_INF;
            INS5(c0, m, sgv[0], sgi[0]);
            float c1 = h1[reg] * S28 + l1[reg] * S40;
            c1 = ok ? c1 : NEG_INF;
            INS5(c1, m, sgv[1], sgi[1]);
        }
    }

    // write segments to LDS: row = tile*16+jr, seg = w*4+q
    int seg = w * 4 + q;
#pragma unroll
    for (int tile = 0; tile < 2; ++tile) {
        int row = tile * 16 + jr;
        int base = (row * 16 + seg) * 5;
#pragma unroll
        for (int k = 0; k < 5; ++k) { svf[base + k] = sgv[tile][k]; sii[base + k] = sgi[tile][k]; }
    }
    __syncthreads();

    // merge: wave 0, two lanes per row (t and t+32), 8 segments each
    if (t < 64) {
        int row = t & 31, half = t >> 5;
        float fv[9]; int fi[9];
#pragma unroll
        for (int k = 0; k < 9; ++k) { fv[k] = NEG_INF; fi[k] = 0x7fffffff; }
        float mv = NEG_INF; int mi = 0x7fffffff; int mp = 0;
        for (int s = half * 8; s < half * 8 + 8; ++s) {
            int base = (row * 16 + s) * 5;
#pragma unroll
            for (int k = 0; k < 5; ++k) ins9(svf[base + k], sii[base + k], fv, fi, mv, mi, mp);
        }
        // combine halves via shfl (both lanes active)
        float pv[9]; int pi[9];
#pragma unroll
        for (int k = 0; k < 9; ++k) { pv[k] = __shfl_xor(fv[k], 32); pi[k] = __shfl_xor(fi[k], 32); }
#pragma unroll
        for (int k = 0; k < 9; ++k) ins9(pv[k], pi[k], fv, fi, mv, mi, mp);

        if (t < 32) {
            int r = r0 + row;
            if (r < NN) {
                // detection: any segment's kept-5th strictly beats the merged 9th
                bool bad = false;
#pragma unroll 4
                for (int s = 0; s < 16; ++s) {
                    float v4 = svf[(row * 16 + s) * 5 + 4];
                    int   i4 = sii[(row * 16 + s) * 5 + 4];
                    bad = bad || (v4 > mv) || (v4 == mv && i4 < mi);
                }
                if (bad) {
                    int pos = atomicAdd(badcnt, 1);
                    if (pos < BADCAP) badlist[pos] = (b << 12) | r;
                }
                float s = 1e-6f;
#pragma unroll
                for (int k = 0; k < 9; ++k) s += fv[k];
                float inv = 1.0f / s;
                int base = (b * NN + r) * KK;
#pragma unroll
                for (int k = 0; k < 9; ++k) { vout[base + k] = fv[k] * inv; iout[base + k] = fi[k]; }
            }
        }
    }
}

// ---------------- Kernel 2b: exact re-solve of flagged rows (fast, vectorized) ----------------
__global__ __launch_bounds__(256) void k_topk_fix(const f16* __restrict__ xh, const f16* __restrict__ xl,
                                                  const int* __restrict__ badcnt, const int* __restrict__ badlist,
                                                  float* __restrict__ vout, int* __restrict__ iout) {
    __shared__ float shr[CC], slr[CC];     // reference row h/l as float
    __shared__ float wvs[4][9];
    __shared__ int   wis[4][9];
    int nb = min(badcnt[0], BADCAP);
    int t = threadIdx.x, w = t >> 6, lane = t & 63;
    for (int i = blockIdx.x; i < nb; i += gridDim.x) {
        __syncthreads();
        int id = badlist[i];
        int b = id >> 12, r = id & 4095;
        if (t < CC) {
            shr[t] = (float)xh[((size_t)b * NN + r) * CC + t];
            slr[t] = (float)xl[((size_t)b * NN + r) * CC + t];
        }
        __syncthreads();
        float fv[9]; int fi[9];
#pragma unroll
        for (int k = 0; k < 9; ++k) { fv[k] = NEG_INF; fi[k] = 0x7fffffff; }
        float mv = NEG_INF; int mi = 0x7fffffff; int mp = 0;
        for (int m = t; m < NN; m += 256) {
            const f16x8* mH = (const f16x8*)(xh + ((size_t)b * NN + m) * CC);
            const f16x8* mL = (const f16x8*)(xl + ((size_t)b * NN + m) * CC);
            float a1 = 0.f, a2 = 0.f;
#pragma unroll
            for (int e = 0; e < 16; ++e) {
                f16x8 hv = mH[e], lv = mL[e];
#pragma unroll
                for (int j = 0; j < 8; ++j) {
                    float hm = (float)hv[j], lm = (float)lv[j];
                    float hr = shr[e * 8 + j], lr = slr[e * 8 + j];
                    a1 += hr * hm;
                    a2 += hr * lm + lr * hm;
                }
            }
            ins9(a1 * S28 + a2 * S40, m, fv, fi, mv, mi, mp);
        }
#pragma unroll
        for (int off = 1; off < 64; off <<= 1) {
            float pv[9]; int pi[9];
#pragma unroll
            for (int k = 0; k < 9; ++k) { pv[k] = __shfl_xor(fv[k], off); pi[k] = __shfl_xor(fi[k], off); }
#pragma unroll
            for (int k = 0; k < 9; ++k) ins9(pv[k], pi[k], fv, fi, mv, mi, mp);
        }
        if (lane == 0) {
#pragma unroll
            for (int k = 0; k < 9; ++k) { wvs[w][k] = fv[k]; wis[w][k] = fi[k]; }
        }
        __syncthreads();
        if (t == 0) {
            for (int ww = 1; ww < 4; ++ww)
#pragma unroll
                for (int k = 0; k < 9; ++k) ins9(wvs[ww][k], wis[ww][k], fv, fi, mv, mi, mp);
            float s = 1e-6f;
#pragma unroll
            for (int k = 0; k < 9; ++k) s += fv[k];
            float inv = 1.0f / s;
            int base = (b * NN + r) * KK;
#pragma unroll
            for (int k = 0; k < 9; ++k) { vout[base + k] = fv[k] * inv; iout[base + k] = fi[k]; }
        }
    }
}

// ---------------- Kernel 3a: GEMM out = reconstruct(xh,xl) @ w  (layer 1) ----------------
#define RST 36
__global__ __launch_bounds__(256) void k_gemm_hl(const f16* __restrict__ xh, const f16* __restrict__ xl,
                                                 const float* __restrict__ w, float* __restrict__ out) {
    __shared__ float rowsT[CC * RST];
    int t = threadIdx.x;
    int row0 = blockIdx.x * 32;
    for (int it = 0; it < 16; ++it) {
        int qq = t + it * 256;
        int c = qq & 127, r = qq >> 7;
        size_t idx = (size_t)(row0 + r) * CC + c;
        rowsT[c * RST + r] = (float)xh[idx] * RH + (float)xl[idx] * RL;
    }
    __syncthreads();
    int j = t & 127, half = t >> 7;
    float acc[16];
#pragma unroll
    for (int r = 0; r < 16; ++r) acc[r] = 0.0f;
    for (int c = 0; c < CC; ++c) {
        float wv = w[c * CC + j];
        const float4* ap = (const float4*)&rowsT[c * RST + half * 16];
        float4 a0 = ap[0], a1 = ap[1], a2 = ap[2], a3 = ap[3];
        acc[0]  += a0.x * wv; acc[1]  += a0.y * wv; acc[2]  += a0.z * wv; acc[3]  += a0.w * wv;
        acc[4]  += a1.x * wv; acc[5]  += a1.y * wv; acc[6]  += a1.z * wv; acc[7]  += a1.w * wv;
        acc[8]  += a2.x * wv; acc[9]  += a2.y * wv; acc[10] += a2.z * wv; acc[11] += a2.w * wv;
        acc[12] += a3.x * wv; acc[13] += a3.y * wv; acc[14] += a3.z * wv; acc[15] += a3.w * wv;
    }
#pragma unroll
    for (int r = 0; r < 16; ++r) out[(size_t)(row0 + half * 16 + r) * CC + j] = acc[r];
}

// ---------------- Kernel 3b: GEMM fp32 in (layer 2) ----------------
__global__ __launch_bounds__(256) void k_gemm(const float* __restrict__ in,
                                              const float* __restrict__ w,
                                              float* __restrict__ out) {
    __shared__ float rowsT[CC * RST];
    int t = threadIdx.x;
    int row0 = blockIdx.x * 32;
    for (int it = 0; it < 16; ++it) {
        int qq = t + it * 256;
        int c = qq & 127, r = qq >> 7;
        rowsT[c * RST + r] = in[(size_t)(row0 + r) * CC + c];
    }
    __syncthreads();
    int j = t & 127, half = t >> 7;
    float acc[16];
#pragma unroll
    for (int r = 0; r < 16; ++r) acc[r] = 0.0f;
    for (int c = 0; c < CC; ++c) {
        float wv = w[c * CC + j];
        const float4* ap = (const float4*)&rowsT[c * RST + half * 16];
        float4 a0 = ap[0], a1 = ap[1], a2 = ap[2], a3 = ap[3];
        acc[0]  += a0.x * wv; acc[1]  += a0.y * wv; acc[2]  += a0.z * wv; acc[3]  += a0.w * wv;
        acc[4]  += a1.x * wv; acc[5]  += a1.y * wv; acc[6]  += a1.z * wv; acc[7]  += a1.w * wv;
        acc[8]  += a2.x * wv; acc[9]  += a2.y * wv; acc[10] += a2.z * wv; acc[11] += a2.w * wv;
        acc[12] += a3.x * wv; acc[13] += a3.y * wv; acc[14] += a3.z * wv; acc[15] += a3.w * wv;
    }
#pragma unroll
    for (int r = 0; r < 16; ++r) out[(size_t)(row0 + half * 16 + r) * CC + j] = acc[r];
}

// ---------------- Kernel 4: gather + weighted sum + bias ----------------
__global__ __launch_bounds__(256) void k_gather(const float* __restrict__ xt,
                                                const float* __restrict__ v,
                                                const int* __restrict__ idx,
                                                const float* __restrict__ bias,
                                                float* __restrict__ out) {
    int t = threadIdx.x;
    int g = blockIdx.x * 2 + (t >> 7);
    int c = t & 127;
    if (g >= ROWS_TOTAL) return;
    int b = g / NN;
    int nb = b * NN;
    float acc = bias[c];
    int base = g * KK;
#pragma unroll
    for (int k = 0; k < KK; ++k) {
        int   ii = idx[base + k];
        float vv = v[base + k];
        acc += vv * xt[(size_t)(nb + ii) * CC + c];
    }
    out[(size_t)g * CC + c] = acc;
}

// ---------------- Kernel 5: GroupNorm stats per (b, group) ----------------
__global__ __launch_bounds__(256) void k_gnstats(const float* __restrict__ xin,
                                                 float* __restrict__ stats) {
    int bg = blockIdx.x; int b = bg >> 2; int gg = bg & 3;
    size_t base = (size_t)b * (NN * CC) + gg * CPG;
    float s1 = 0.f, s2 = 0.f;
    for (int i = threadIdx.x; i < NN * CPG; i += 256) {
        float x = xin[base + (size_t)(i >> 5) * CC + (i & 31)];
        s1 += x; s2 += x * x;
    }
#pragma unroll
    for (int off = 32; off > 0; off >>= 1) { s1 += __shfl_xor(s1, off); s2 += __shfl_xor(s2, off); }
    __shared__ float r1[4], r2[4];
    int w = threadIdx.x >> 6;
    if ((threadIdx.x & 63) == 0) { r1[w] = s1; r2[w] = s2; }
    __syncthreads();
    if (threadIdx.x == 0) {
        float a = r1[0] + r1[1] + r1[2] + r1[3];
        float qq = r2[0] + r2[1] + r2[2] + r2[3];
        const float inv = 1.0f / (float)(NN * CPG);
        float mean = a * inv;
        float var = qq * inv - mean * mean;
        stats[bg * 2]     = mean;
        stats[bg * 2 + 1] = rsqrtf(fmaxf(var, 0.f) + GN_EPS);
    }
}

// ---------------- Kernel 6: GN apply + SiLU (layout-preserving, fp32 out) ----------------
__global__ __launch_bounds__(256) void k_gnsilu(const float* __restrict__ xin,
                                                const float* __restrict__ stats,
                                                const float* __restrict__ gamma,
                                                const float* __restrict__ beta,
                                                float* __restrict__ out) {
    size_t e4 = ((size_t)blockIdx.x * 256 + threadIdx.x) * 4;
    int c0 = (int)(e4 & 127);
    int b  = (int)(e4 / (NN * CC));
    int gg = c0 >> 5;
    float mean = stats[(b * 4 + gg) * 2];
    float rstd = stats[(b * 4 + gg) * 2 + 1];
    float4 x = *(const float4*)&xin[e4];
    float g0 = gamma[c0], g1 = gamma[c0 + 1], g2 = gamma[c0 + 2], g3 = gamma[c0 + 3];
    float p0 = beta[c0],  p1 = beta[c0 + 1],  p2 = beta[c0 + 2],  p3 = beta[c0 + 3];
    float y0 = (x.x - mean) * rstd * g0 + p0;
    float y1 = (x.y - mean) * rstd * g1 + p1;
    float y2 = (x.z - mean) * rstd * g2 + p2;
    float y3 = (x.w - mean) * rstd * g3 + p3;
    float4 r;
    r.x = y0 / (1.0f + expf(-y0));
    r.y = y1 / (1.0f + expf(-y1));
    r.z = y2 / (1.0f + expf(-y2));
    r.w = y3 / (1.0f + expf(-y3));
    *(float4*)&out[e4] = r;
}

// ---------------- Kernel 7: GN apply + SiLU + transpose to [B][C][N], fp32 out ----------------
__global__ __launch_bounds__(256) void k_gnsilu_out(const float* __restrict__ xin,
                                                    const float* __restrict__ stats,
                                                    const float* __restrict__ gamma,
                                                    const float* __restrict__ beta,
                                                    float* __restrict__ out) {
    __shared__ float tile[32 * 65];
    int b = blockIdx.z, ct = blockIdx.y, nt = blockIdx.x;
    int c0 = ct * 32, n0 = nt * 64;
    int t = threadIdx.x;
    int cj = t & 31, ni0 = t >> 5;
    int gg = c0 >> 5;
    float mean = stats[(b * 4 + gg) * 2];
    float rstd = stats[(b * 4 + gg) * 2 + 1];
    float gm = gamma[c0 + cj];
    float bt = beta[c0 + cj];
#pragma unroll
    for (int i = 0; i < 8; ++i) {
        int n = n0 + ni0 + i * 8;
        if (n < NN) {
            float x = xin[((size_t)b * NN + n) * CC + c0 + cj];
            float y = (x - mean) * rstd * gm + bt;
            y = y / (1.0f + expf(-y));
            tile[cj * 65 + ni0 + i * 8] = y;
        }
    }
    __syncthreads();
    int nj = t & 63, ci0 = t >> 6;
#pragma unroll
    for (int i = 0; i < 8; ++i) {
        int c = ci0 + i * 4;
        int n = n0 + nj;
        if (n < NN) out[((size_t)b * CC + c0 + c) * NN + n] = tile[c * 65 + nj];
    }
}

extern "C" void kernel_launch(void* const* d_in, const int* in_sizes, int n_in,
                              void* d_out, int out_size, void* d_ws, size_t ws_size,
                              hipStream_t stream) {
    const float* x      = (const float*)d_in[0];
    const float* w1     = (const float*)d_in[1];
    const float* b1     = (const float*)d_in[2];
    const float* w2     = (const float*)d_in[3];
    const float* b2     = (const float*)d_in[4];
    const float* gamma1 = (const float*)d_in[5];
    const float* beta1  = (const float*)d_in[6];
    const float* gamma2 = (const float*)d_in[7];
    const float* beta2  = (const float*)d_in[8];
    float* out = (float*)d_out;

    const size_t BIG = (size_t)ROWS_TOTAL * CC;   // 8,294,400
    float* ws   = (float*)d_ws;
    float* bufB = ws;                              // gemm1out -> feat2 -> gath2
    f16*   xh   = (f16*)(ws + BIG);                // f16 split hi
    f16*   xl   = xh + BIG;                        // f16 split lo
    float* bufA = ws + BIG;                        // ALIASES xh/xl; first written by gather1
    float* vbuf = ws + 2 * BIG;                    // [64800*9]
    int*   ibuf = (int*)(ws + 2 * BIG + (size_t)ROWS_TOTAL * KK);
    float* stats = ws + 2 * BIG + 2 * (size_t)ROWS_TOTAL * KK;
    int*   badcnt  = (int*)(stats + 256);
    int*   badlist = badcnt + 1;

    hipMemsetAsync(badcnt, 0, sizeof(int), stream);

    k_normalize<<<dim3(32, BN), 256, 0, stream>>>(x, xh, xl);
    k_sim_topk<<<dim3(64, BN), 256, 0, stream>>>(xh, xl, vbuf, ibuf, badcnt, badlist);
    k_topk_fix<<<64, 256, 0, stream>>>(xh, xl, badcnt, badlist, vbuf, ibuf);

    // layer 1 (xh/xl last read by k_gemm_hl; bufA aliases them and is written after)
    k_gemm_hl<<<(ROWS_TOTAL + 31) / 32, 256, 0, stream>>>(xh, xl, w1, bufB);
    k_gather<<<ROWS_TOTAL / 2, 256, 0, stream>>>(bufB, vbuf, ibuf, b1, bufA);
    k_gnstats<<<BN * NGROUP, 256, 0, stream>>>(bufA, stats);
    k_gnsilu<<<(int)(BIG / 1024), 256, 0, stream>>>(bufA, stats, gamma1, beta1, bufB);

    // layer 2
    k_gemm<<<(ROWS_TOTAL + 31) / 32, 256, 0, stream>>>(bufB, w2, bufA);
    k_gather<<<ROWS_TOTAL / 2, 256, 0, stream>>>(bufA, vbuf, ibuf, b2, bufB);
    k_gnstats<<<BN * NGROUP, 256, 0, stream>>>(bufB, stats);
    k_gnsilu_out<<<dim3((NN + 63) / 64, NGROUP, BN), 256, 0, stream>>>(bufB, stats, gamma2, beta2, out);
}